// Round 3
// baseline (1350.991 us; speedup 1.0000x reference)
//
#include <hip/hip_runtime.h>
#include <cstdint>
#include <cstddef>

#define DD 300
#define D4 75   // DD/4 float4s per row

// ---------------- index dtype detection ----------------
// Indices may be int32 or int64 (if harness ran with jax_enable_x64).
// Read only the first nE int32 words of each buffer (in-bounds either way).
// If int64: words are (lo,hi,lo,hi,...) with hi==0 (values < 50000) -> OR of odd words == 0.
// If int32: odd words are random edge ids -> OR != 0 w.p. 1.
__global__ void detect_kernel(const unsigned int* __restrict__ a,
                              const unsigned int* __restrict__ b,
                              int nWords, unsigned int* __restrict__ flag) {
    unsigned int v = 0;
    int stride = gridDim.x * blockDim.x;
    for (int i = blockIdx.x * blockDim.x + threadIdx.x; i < nWords / 2; i += stride) {
        v |= a[2 * i + 1] | b[2 * i + 1];
    }
    if (v) atomicOr(flag, 1u);
}

__device__ __forceinline__ int load_idx(const void* p, int e, bool is64) {
    return is64 ? (int)((const long long*)p)[e] : ((const int*)p)[e];
}

// ---------------- CSR build ----------------

__global__ void hist_kernel(const void* __restrict__ dst, const unsigned int* __restrict__ flag,
                            int* __restrict__ counts, int nE) {
    int e = blockIdx.x * blockDim.x + threadIdx.x;
    if (e < nE) {
        bool is64 = (*flag == 0u);
        atomicAdd(&counts[load_idx(dst, e, is64)], 1);
    }
}

// Single block, 1024 threads. In: cnt_cursor = per-node counts.
// Out: offsets[0..n] = exclusive scan (+ total at [n]); cnt_cursor rewritten to
// the same exclusive offsets (used as running cursors by fill_kernel).
__global__ void scan_kernel(int* __restrict__ cnt_cursor, int* __restrict__ offsets, int n) {
    __shared__ int sums[1024];
    int t = threadIdx.x;
    int CH = (n + 1023) >> 10;
    int base = t * CH;
    int s = 0;
    for (int i = 0; i < CH; ++i) {
        int idx = base + i;
        if (idx < n) s += cnt_cursor[idx];
    }
    sums[t] = s;
    __syncthreads();
    for (int off = 1; off < 1024; off <<= 1) {
        int v = (t >= off) ? sums[t - off] : 0;
        __syncthreads();
        sums[t] += v;
        __syncthreads();
    }
    int run = (t == 0) ? 0 : sums[t - 1];
    for (int i = 0; i < CH; ++i) {
        int idx = base + i;
        if (idx < n) {
            int c = cnt_cursor[idx];
            offsets[idx] = run;
            cnt_cursor[idx] = run;
            run += c;
        }
    }
    if (t == 1023) offsets[n] = sums[1023];
}

__global__ void fill_kernel(const void* __restrict__ src, const void* __restrict__ dst,
                            const unsigned int* __restrict__ flag,
                            int* __restrict__ cursor, int* __restrict__ eidx, int nE) {
    int e = blockIdx.x * blockDim.x + threadIdx.x;
    if (e < nE) {
        bool is64 = (*flag == 0u);
        int d = load_idx(dst, e, is64);
        int s = load_idx(src, e, is64);
        int pos = atomicAdd(&cursor[d], 1);
        eidx[pos] = s;
    }
}

// ---------------- aggregation: agg[v] = sum_{u in in-neighbors(v)} x[u] ----------------
// one wave per node; float4 coalesced row reads (75 float4 per row)

__global__ __launch_bounds__(64) void agg_kernel(const float* __restrict__ x,
                                                 const int* __restrict__ eidx,
                                                 const int* __restrict__ offsets,
                                                 float* __restrict__ agg) {
    int v = blockIdx.x;
    int lane = threadIdx.x;
    int beg = offsets[v], end = offsets[v + 1];
    float a0x = 0.f, a0y = 0.f, a0z = 0.f, a0w = 0.f;
    float a1x = 0.f, a1y = 0.f, a1z = 0.f, a1w = 0.f;
    const float4* x4 = (const float4*)x;
    for (int i = beg; i < end; ++i) {
        int u = eidx[i];
        const float4* row = x4 + (size_t)u * D4;
        float4 p = row[lane];
        a0x += p.x; a0y += p.y; a0z += p.z; a0w += p.w;
        if (lane < D4 - 64) {
            float4 q = row[64 + lane];
            a1x += q.x; a1y += q.y; a1z += q.z; a1w += q.w;
        }
    }
    float4* o4 = (float4*)agg + (size_t)v * D4;
    float4 r0; r0.x = a0x; r0.y = a0y; r0.z = a0z; r0.w = a0w;
    o4[lane] = r0;
    if (lane < D4 - 64) {
        float4 r1; r1.x = a1x; r1.y = a1y; r1.z = a1z; r1.w = a1w;
        o4[64 + lane] = r1;
    }
}

// ---------------- fused GEMM: C = act(A1 @ W[:, 0:300].T (+ A2 @ W[:,300:600].T) + b) ----------------
// A row-major [M,300], W row-major [300, Wld]. NT layout: both K-contiguous.
// ACT: 0 = leaky_relu(0.01), 1 = none, 2 = tanh + global sumsq atomic

template<int ACT>
__global__ __launch_bounds__(256)
void gemm_kernel(const float* __restrict__ A1, const float* __restrict__ A2,
                 const float* __restrict__ W, const float* __restrict__ bias,
                 float* __restrict__ C, int M, int Wld, float* __restrict__ sumsq) {
    constexpr int BM = 128, BN = 64, BK = 32;
    __shared__ __align__(16) float As[BK][BM + 4];  // stride 132 floats = 528B (16B mult)
    __shared__ __align__(16) float Bs[BK][BN + 4];  // stride 68 floats = 272B (16B mult)
    __shared__ float red[256];

    const int t = threadIdx.x;
    const int tx = t & 15;        // 16 col-groups
    const int ty = t >> 4;        // 16 row-groups
    const int m0 = blockIdx.y * BM;
    const int col0 = blockIdx.x * BN;

    float acc[8][4];
#pragma unroll
    for (int i = 0; i < 8; ++i)
#pragma unroll
        for (int j = 0; j < 4; ++j) acc[i][j] = 0.f;

    const int nseg = (A2 != nullptr) ? 2 : 1;
    for (int seg = 0; seg < nseg; ++seg) {
        const float* __restrict__ A = (seg == 0) ? A1 : A2;
        const int koff = seg * DD;
        for (int k0 = 0; k0 < DD; k0 += BK) {
            // stage A: 128 rows x 32 k = 1024 float4, 4 per thread (transposed into LDS)
#pragma unroll
            for (int p = 0; p < 4; ++p) {
                int f = t + 256 * p;
                int r = f >> 3;
                int kq = f & 7;
                int row = m0 + r;
                int kcol = k0 + kq * 4;
                float4 v; v.x = 0.f; v.y = 0.f; v.z = 0.f; v.w = 0.f;
                if (row < M && kcol < DD)
                    v = *(const float4*)(A + (size_t)row * DD + kcol);
                As[kq * 4 + 0][r] = v.x;
                As[kq * 4 + 1][r] = v.y;
                As[kq * 4 + 2][r] = v.z;
                As[kq * 4 + 3][r] = v.w;
            }
            // stage B: 64 cols x 32 k = 512 float4, 2 per thread (ALL 256 threads)
#pragma unroll
            for (int p = 0; p < 2; ++p) {
                int f = t + 256 * p;   // 0..511
                int c = f >> 3;        // 0..63
                int kq = f & 7;        // 0..7
                int col = col0 + c;
                int kcol = k0 + kq * 4;
                float4 v; v.x = 0.f; v.y = 0.f; v.z = 0.f; v.w = 0.f;
                if (col < DD && kcol < DD)
                    v = *(const float4*)(W + (size_t)col * Wld + koff + kcol);
                Bs[kq * 4 + 0][c] = v.x;
                Bs[kq * 4 + 1][c] = v.y;
                Bs[kq * 4 + 2][c] = v.z;
                Bs[kq * 4 + 3][c] = v.w;
            }
            __syncthreads();
#pragma unroll
            for (int kk = 0; kk < BK; ++kk) {
                float4 a0 = *(const float4*)&As[kk][ty * 8];
                float4 a1 = *(const float4*)&As[kk][ty * 8 + 4];
                float4 b = *(const float4*)&Bs[kk][tx * 4];
                float av[8] = {a0.x, a0.y, a0.z, a0.w, a1.x, a1.y, a1.z, a1.w};
                float bv[4] = {b.x, b.y, b.z, b.w};
#pragma unroll
                for (int i = 0; i < 8; ++i)
#pragma unroll
                    for (int j = 0; j < 4; ++j)
                        acc[i][j] = fmaf(av[i], bv[j], acc[i][j]);
            }
            __syncthreads();
        }
    }

    // epilogue
    const int col = col0 + tx * 4;
    const bool colok = (col < DD);  // col mult of 4, DD mult of 4 -> full float4 valid
    float4 b4; b4.x = 0.f; b4.y = 0.f; b4.z = 0.f; b4.w = 0.f;
    if (colok) b4 = *(const float4*)(bias + col);
    float ss = 0.f;
#pragma unroll
    for (int i = 0; i < 8; ++i) {
        int row = m0 + ty * 8 + i;
        if (colok && row < M) {
            float4 o;
            o.x = acc[i][0] + b4.x;
            o.y = acc[i][1] + b4.y;
            o.z = acc[i][2] + b4.z;
            o.w = acc[i][3] + b4.w;
            if (ACT == 0) {
                o.x = o.x > 0.f ? o.x : 0.01f * o.x;
                o.y = o.y > 0.f ? o.y : 0.01f * o.y;
                o.z = o.z > 0.f ? o.z : 0.01f * o.z;
                o.w = o.w > 0.f ? o.w : 0.01f * o.w;
            } else if (ACT == 2) {
                o.x = tanhf(o.x); o.y = tanhf(o.y); o.z = tanhf(o.z); o.w = tanhf(o.w);
                ss += o.x * o.x + o.y * o.y + o.z * o.z + o.w * o.w;
            }
            *(float4*)(C + (size_t)row * DD + col) = o;
        }
    }
    if (ACT == 2) {
        red[t] = ss;
        __syncthreads();
        for (int s = 128; s > 0; s >>= 1) {
            if (t < s) red[t] += red[t + s];
            __syncthreads();
        }
        if (t == 0) atomicAdd(sumsq, red[0]);
    }
}

__global__ void norm_kernel(float* __restrict__ out, const float* __restrict__ sumsq, int n4) {
    int i = blockIdx.x * blockDim.x + threadIdx.x;
    if (i < n4) {
        float inv = rsqrtf(*sumsq);
        float4* o = (float4*)out;
        float4 v = o[i];
        v.x *= inv; v.y *= inv; v.z *= inv; v.w *= inv;
        o[i] = v;
    }
}

// ---------------- launch ----------------

extern "C" void kernel_launch(void* const* d_in, const int* in_sizes, int n_in,
                              void* d_out, int out_size, void* d_ws, size_t ws_size,
                              hipStream_t stream) {
    const float* feat = (const float*)d_in[0];
    const void* src = d_in[1];
    const void* dst = d_in[2];
    const float* W1 = (const float*)d_in[3];
    const float* b1 = (const float*)d_in[4];
    const float* W2 = (const float*)d_in[5];
    const float* b2 = (const float*)d_in[6];
    const float* W3 = (const float*)d_in[7];
    const float* b3 = (const float*)d_in[8];
    float* out = (float*)d_out;

    const int M = in_sizes[0] / DD;    // 50000
    const int nE = in_sizes[1];        // 800000

    char* ws = (char*)d_ws;
    size_t off = 0;
    auto alloc = [&](size_t bytes) -> void* {
        off = (off + 255) & ~(size_t)255;
        void* p = ws + off;
        off += bytes;
        return p;
    };
    int* eidx = (int*)alloc((size_t)nE * 4);
    int* offsets = (int*)alloc((size_t)(M + 1) * 4);
    int* cursor = (int*)alloc((size_t)M * 4);
    float* sumsq = (float*)alloc(4);
    unsigned int* flag = (unsigned int*)alloc(4);
    float* agg = (float*)alloc((size_t)M * DD * 4);
    float* x2 = (float*)alloc((size_t)M * DD * 4);
    float* x1 = out;  // use d_out as layer-1 activation scratch (fully overwritten by G3)
    (void)ws_size; (void)n_in; (void)out_size;

    hipMemsetAsync(cursor, 0, (size_t)M * 4, stream);
    hipMemsetAsync(sumsq, 0, 4, stream);
    hipMemsetAsync(flag, 0, 4, stream);

    const int tb = 256;
    detect_kernel<<<256, tb, 0, stream>>>((const unsigned int*)src, (const unsigned int*)dst,
                                          nE, flag);
    hist_kernel<<<(nE + tb - 1) / tb, tb, 0, stream>>>(dst, flag, cursor, nE);
    scan_kernel<<<1, 1024, 0, stream>>>(cursor, offsets, M);
    fill_kernel<<<(nE + tb - 1) / tb, tb, 0, stream>>>(src, dst, flag, cursor, eidx, nE);

    dim3 ggrid((DD + 63) / 64, (M + 127) / 128);

    // layer 1
    agg_kernel<<<M, 64, 0, stream>>>(feat, eidx, offsets, agg);
    gemm_kernel<0><<<ggrid, 256, 0, stream>>>(feat, agg, W1, b1, x1, M, 2 * DD, nullptr);
    // layer 2
    agg_kernel<<<M, 64, 0, stream>>>(x1, eidx, offsets, agg);
    gemm_kernel<1><<<ggrid, 256, 0, stream>>>(x1, agg, W2, b2, x2, M, 2 * DD, nullptr);
    // output layer + tanh + sumsq
    gemm_kernel<2><<<ggrid, 256, 0, stream>>>(x2, nullptr, W3, b3, out, M, DD, sumsq);
    // global frobenius normalize
    int n4 = (M * DD) / 4;
    norm_kernel<<<(n4 + tb - 1) / tb, tb, 0, stream>>>(out, sumsq, n4);
}

// Round 4
// 1075.611 us; speedup vs baseline: 1.2560x; 1.2560x over previous
//
#include <hip/hip_runtime.h>
#include <cstdint>
#include <cstddef>

typedef unsigned short u16;
typedef __attribute__((ext_vector_type(8))) short short8;
typedef __attribute__((ext_vector_type(4))) float f32x4;

#define DD 300
#define KPAD 304           // activation row length in bf16 (608 B rows)
#define BM 128
#define BN 64

__device__ __forceinline__ u16 f2bf(float f) {
    unsigned u = __float_as_uint(f);
    unsigned r = (u + 0x7fffu + ((u >> 16) & 1u)) >> 16;   // RNE
    return (u16)r;
}
__device__ __forceinline__ float bf2f(u16 h) {
    return __uint_as_float((unsigned)h << 16);
}

#define GLOAD16(SRC, DST) \
    __builtin_amdgcn_global_load_lds((const __attribute__((address_space(1))) void*)(SRC), \
                                     (__attribute__((address_space(3))) void*)(DST), 16, 0, 0)

// ---------------- index dtype detection (int32 vs int64 indices) ----------------
__global__ void detect_kernel(const unsigned int* __restrict__ a,
                              const unsigned int* __restrict__ b,
                              int nWords, unsigned int* __restrict__ flag) {
    unsigned int v = 0;
    int stride = gridDim.x * blockDim.x;
    for (int i = blockIdx.x * blockDim.x + threadIdx.x; i < nWords / 2; i += stride)
        v |= a[2 * i + 1] | b[2 * i + 1];
    if (v) atomicOr(flag, 1u);
}

__device__ __forceinline__ int load_idx(const void* p, int e, bool is64) {
    return is64 ? (int)((const long long*)p)[e] : ((const int*)p)[e];
}

// ---------------- CSR build ----------------
__global__ void hist_kernel(const void* __restrict__ dst, const unsigned int* __restrict__ flag,
                            int* __restrict__ counts, int nE) {
    int e = blockIdx.x * blockDim.x + threadIdx.x;
    if (e < nE) {
        bool is64 = (*flag == 0u);
        atomicAdd(&counts[load_idx(dst, e, is64)], 1);
    }
}

__global__ void scan_kernel(int* __restrict__ cnt_cursor, int* __restrict__ offsets, int n) {
    __shared__ int sums[1024];
    int t = threadIdx.x;
    int CH = (n + 1023) >> 10;
    int base = t * CH;
    int s = 0;
    for (int i = 0; i < CH; ++i) {
        int idx = base + i;
        if (idx < n) s += cnt_cursor[idx];
    }
    sums[t] = s;
    __syncthreads();
    for (int off = 1; off < 1024; off <<= 1) {
        int v = (t >= off) ? sums[t - off] : 0;
        __syncthreads();
        sums[t] += v;
        __syncthreads();
    }
    int run = (t == 0) ? 0 : sums[t - 1];
    for (int i = 0; i < CH; ++i) {
        int idx = base + i;
        if (idx < n) {
            int c = cnt_cursor[idx];
            offsets[idx] = run;
            cnt_cursor[idx] = run;
            run += c;
        }
    }
    if (t == 1023) offsets[n] = sums[1023];
}

__global__ void fill_kernel(const void* __restrict__ src, const void* __restrict__ dst,
                            const unsigned int* __restrict__ flag,
                            int* __restrict__ cursor, int* __restrict__ eidx, int nE) {
    int e = blockIdx.x * blockDim.x + threadIdx.x;
    if (e < nE) {
        bool is64 = (*flag == 0u);
        int d = load_idx(dst, e, is64);
        int s = load_idx(src, e, is64);
        int pos = atomicAdd(&cursor[d], 1);
        eidx[pos] = s;
    }
}

// ---------------- f32 -> bf16 hi/lo conversion ----------------
__global__ void conv_feat(const float* __restrict__ src, u16* __restrict__ dhi,
                          u16* __restrict__ dlo, int M) {
    int tid = blockIdx.x * blockDim.x + threadIdx.x;
    int total = M * 76;
    if (tid >= total) return;
    int row = tid / 76, cq = tid - row * 76;
    int k = cq * 4;
    float vx = 0.f, vy = 0.f, vz = 0.f, vw = 0.f;
    if (k < DD) {
        float4 v = *(const float4*)(src + (size_t)row * DD + k);
        vx = v.x; vy = v.y; vz = v.z; vw = v.w;
    }
    ushort4 h, l;
    h.x = f2bf(vx); l.x = f2bf(vx - bf2f(h.x));
    h.y = f2bf(vy); l.y = f2bf(vy - bf2f(h.y));
    h.z = f2bf(vz); l.z = f2bf(vz - bf2f(h.z));
    h.w = f2bf(vw); l.w = f2bf(vw - bf2f(h.w));
    *(ushort4*)&dhi[(size_t)row * KPAD + k] = h;
    *(ushort4*)&dlo[(size_t)row * KPAD + k] = l;
}

// W: [300][nseg*300] f32 row-major -> whi/wlo [300][nseg*320] bf16 (zero-padded k 300..319/seg)
__global__ void conv_w(const float* __restrict__ W, u16* __restrict__ whi,
                       u16* __restrict__ wlo, int nseg) {
    int KP = nseg * 320;
    int tid = blockIdx.x * blockDim.x + threadIdx.x;
    if (tid >= 300 * KP) return;
    int n = tid / KP, kk = tid - n * KP;
    int seg = kk / 320, ko = kk - seg * 320;
    float v = (ko < DD) ? W[(size_t)n * (nseg * DD) + seg * DD + ko] : 0.f;
    u16 h = f2bf(v);
    whi[tid] = h;
    wlo[tid] = f2bf(v - bf2f(h));
}

// ---------------- aggregation over bf16 hi/lo planes ----------------
__global__ __launch_bounds__(64)
void agg_bf16(const u16* __restrict__ xhi, const u16* __restrict__ xlo,
              const int* __restrict__ eidx, const int* __restrict__ offsets,
              u16* __restrict__ ohi, u16* __restrict__ olo) {
    int v = blockIdx.x, lane = threadIdx.x;
    int beg = offsets[v], end = offsets[v + 1];
    float am0 = 0.f, am1 = 0.f, am2 = 0.f, am3 = 0.f;
    float at0 = 0.f, at1 = 0.f, at2 = 0.f, at3 = 0.f;
    bool tail = lane < 11;                     // chunks 64..74 cover k 256..299
    for (int i = beg; i < end; ++i) {
        size_t base = (size_t)eidx[i] * KPAD;
        ushort4 h = *(const ushort4*)&xhi[base + lane * 4];
        ushort4 l = *(const ushort4*)&xlo[base + lane * 4];
        am0 += bf2f(h.x) + bf2f(l.x);
        am1 += bf2f(h.y) + bf2f(l.y);
        am2 += bf2f(h.z) + bf2f(l.z);
        am3 += bf2f(h.w) + bf2f(l.w);
        if (tail) {
            ushort4 h2 = *(const ushort4*)&xhi[base + 256 + lane * 4];
            ushort4 l2 = *(const ushort4*)&xlo[base + 256 + lane * 4];
            at0 += bf2f(h2.x) + bf2f(l2.x);
            at1 += bf2f(h2.y) + bf2f(l2.y);
            at2 += bf2f(h2.z) + bf2f(l2.z);
            at3 += bf2f(h2.w) + bf2f(l2.w);
        }
    }
    size_t ob = (size_t)v * KPAD + lane * 4;
    ushort4 oh, ol;
    oh.x = f2bf(am0); ol.x = f2bf(am0 - bf2f(oh.x));
    oh.y = f2bf(am1); ol.y = f2bf(am1 - bf2f(oh.y));
    oh.z = f2bf(am2); ol.z = f2bf(am2 - bf2f(oh.z));
    oh.w = f2bf(am3); ol.w = f2bf(am3 - bf2f(oh.w));
    *(ushort4*)&ohi[ob] = oh;
    *(ushort4*)&olo[ob] = ol;
    if (tail) {
        size_t ob2 = (size_t)v * KPAD + 256 + lane * 4;
        ushort4 oh2, ol2;
        oh2.x = f2bf(at0); ol2.x = f2bf(at0 - bf2f(oh2.x));
        oh2.y = f2bf(at1); ol2.y = f2bf(at1 - bf2f(oh2.y));
        oh2.z = f2bf(at2); ol2.z = f2bf(at2 - bf2f(oh2.z));
        oh2.w = f2bf(at3); ol2.w = f2bf(at3 - bf2f(oh2.w));
        *(ushort4*)&ohi[ob2] = oh2;
        *(ushort4*)&olo[ob2] = ol2;
    }
}

// ---------------- MFMA GEMM: C = act( sum_seg A_seg @ Wseg.T + b ) ----------------
// Split-bf16: per k-tile, 3 products (AhiBhi, AhiBlo, AloBhi) as virtual K-steps.
// A planes: [M][304] bf16 rows (608 B). B planes: [300][nseg*320] bf16.
// ACT 0: leaky_relu -> write bf16 hi/lo planes; 1: identity -> planes; 2: tanh -> f32 out + sumsq.
template<int NSEG, int ACT>
__global__ __launch_bounds__(256)
void mfma_gemm(const u16* __restrict__ A0hi, const u16* __restrict__ A0lo,
               const u16* __restrict__ A1hi, const u16* __restrict__ A1lo,
               const u16* __restrict__ Bhi, const u16* __restrict__ Blo,
               const float* __restrict__ bias, int M, int NB,
               u16* __restrict__ Ohi, u16* __restrict__ Olo,
               float* __restrict__ outf, float* __restrict__ sumsq) {
    constexpr int NSTEP = NSEG * 30;       // (NSEG*10 k-tiles) x 3 products
    constexpr int BROW = NSEG * 640;       // B row bytes
    __shared__ __align__(16) char ldsA[2][8192];   // [oct4][row128] x 16B chunks
    __shared__ __align__(16) char ldsB[2][4096];   // [oct4][col64]
    __shared__ float red[256];

    const int t = threadIdx.x;
    const int w = t >> 6, lane = t & 63;
    const int wm = w >> 1, wn = w & 1;
    const int lr = lane & 15, loct = lane >> 4;

    // XCD-chunked bijective swizzle (m204 form)
    int nwg = gridDim.x;
    int q = nwg >> 3, r = nwg & 7;
    int xc = blockIdx.x & 7, o8 = blockIdx.x >> 3;
    int wg = (xc < r ? xc * (q + 1) : r * (q + 1) + (xc - r) * q) + o8;
    int nt = wg % NB, mt = wg / NB;
    const int m0 = mt * BM, col0 = nt * BN;

    f32x4 acc[4][2];
#pragma unroll
    for (int mi = 0; mi < 4; ++mi)
#pragma unroll
        for (int ni = 0; ni < 2; ++ni) {
            f32x4 z = {0.f, 0.f, 0.f, 0.f};
            acc[mi][ni] = z;
        }

    auto stage = [&](int buf, int s) {
        int p = s % 3, ktg = s / 3;
        int seg = (NSEG == 2) ? (ktg / 10) : 0;
        int kt = (NSEG == 2) ? (ktg - seg * 10) : ktg;
        const u16* Ahp = (NSEG == 2 && seg) ? A1hi : A0hi;
        const u16* Alp = (NSEG == 2 && seg) ? A1lo : A0lo;
        const char* Ap = (const char*)(p < 2 ? Ahp : Alp);
        const char* Bp = (const char*)(p == 1 ? Blo : Bhi);
        int Ak = kt * 64;
        int Bk = seg * 640 + kt * 64;
#pragma unroll
        for (int a2 = 0; a2 < 2; ++a2) {
            int rowi = m0 + a2 * 64 + lane;
            rowi = rowi < M ? rowi : (M - 1);
            const char* srcA = Ap + (size_t)rowi * 608 + Ak + w * 16;
            GLOAD16(srcA, &ldsA[buf][(2 * w + a2) * 1024]);
        }
        int coli = col0 + lane;
        coli = coli < DD ? coli : (DD - 1);
        const char* srcB = Bp + (size_t)coli * BROW + Bk + w * 16;
        GLOAD16(srcB, &ldsB[buf][w * 1024]);
    };

    stage(0, 0);
    for (int s = 0; s < NSTEP; ++s) {
        __syncthreads();                    // drains vmcnt -> buf (s&1) ready
        if (s + 1 < NSTEP) stage((s + 1) & 1, s + 1);
        const char* bA = ldsA[s & 1];
        const char* bB = ldsB[s & 1];
        short8 bf[2];
#pragma unroll
        for (int ni = 0; ni < 2; ++ni)
            bf[ni] = *(const short8*)(bB + (loct * 64 + wn * 32 + ni * 16 + lr) * 16);
#pragma unroll
        for (int mi = 0; mi < 4; ++mi) {
            short8 af = *(const short8*)(bA + (loct * 128 + wm * 64 + mi * 16 + lr) * 16);
            acc[mi][0] = __builtin_amdgcn_mfma_f32_16x16x32_bf16(af, bf[0], acc[mi][0], 0, 0, 0);
            acc[mi][1] = __builtin_amdgcn_mfma_f32_16x16x32_bf16(af, bf[1], acc[mi][1], 0, 0, 0);
        }
    }

    // epilogue: C row = m0 + wm*64 + mi*16 + loct*4 + rg ; col = col0 + wn*32 + ni*16 + lr
    float ss = 0.f;
#pragma unroll
    for (int mi = 0; mi < 4; ++mi)
#pragma unroll
        for (int ni = 0; ni < 2; ++ni) {
            int col = col0 + wn * 32 + ni * 16 + lr;
            bool cok = col < DD;
            float bv = cok ? bias[col] : 0.f;
#pragma unroll
            for (int rg = 0; rg < 4; ++rg) {
                int row = m0 + wm * 64 + mi * 16 + loct * 4 + rg;
                if (cok && row < M) {
                    float v = acc[mi][ni][rg] + bv;
                    if (ACT == 0) v = v > 0.f ? v : 0.01f * v;
                    if (ACT <= 1) {
                        u16 h = f2bf(v);
                        u16 l = f2bf(v - bf2f(h));
                        Ohi[(size_t)row * KPAD + col] = h;
                        Olo[(size_t)row * KPAD + col] = l;
                    } else {
                        float tv = tanhf(v);
                        outf[(size_t)row * DD + col] = tv;
                        ss += tv * tv;
                    }
                }
            }
        }
    if (ACT == 2) {
        red[t] = ss;
        __syncthreads();
        for (int s2 = 128; s2 > 0; s2 >>= 1) {
            if (t < s2) red[t] += red[t + s2];
            __syncthreads();
        }
        if (t == 0) atomicAdd(sumsq, red[0]);
    }
}

__global__ void norm_kernel(float* __restrict__ out, const float* __restrict__ sumsq, int n4) {
    int i = blockIdx.x * blockDim.x + threadIdx.x;
    if (i < n4) {
        float inv = rsqrtf(*sumsq);
        float4* o = (float4*)out;
        float4 v = o[i];
        v.x *= inv; v.y *= inv; v.z *= inv; v.w *= inv;
        o[i] = v;
    }
}

// ---------------- launch ----------------
extern "C" void kernel_launch(void* const* d_in, const int* in_sizes, int n_in,
                              void* d_out, int out_size, void* d_ws, size_t ws_size,
                              hipStream_t stream) {
    const float* feat = (const float*)d_in[0];
    const void* src = d_in[1];
    const void* dst = d_in[2];
    const float* W1 = (const float*)d_in[3];
    const float* b1 = (const float*)d_in[4];
    const float* W2 = (const float*)d_in[5];
    const float* b2 = (const float*)d_in[6];
    const float* W3 = (const float*)d_in[7];
    const float* b3 = (const float*)d_in[8];
    float* out = (float*)d_out;

    const int M = in_sizes[0] / DD;    // 50000
    const int nE = in_sizes[1];        // 800000

    char* ws = (char*)d_ws;
    size_t off = 0;
    auto alloc = [&](size_t bytes) -> void* {
        off = (off + 255) & ~(size_t)255;
        void* p = ws + off;
        off += bytes;
        return p;
    };
    const size_t planeB = (size_t)M * KPAD * 2 + 256;   // +slack for kt=9 overread
    int* eidx = (int*)alloc((size_t)nE * 4);
    int* offsets = (int*)alloc((size_t)(M + 1) * 4);
    int* cursor = (int*)alloc((size_t)M * 4);
    float* sumsq = (float*)alloc(4);
    unsigned int* flag = (unsigned int*)alloc(4);
    u16* w1hi = (u16*)alloc(300 * 640 * 2);
    u16* w1lo = (u16*)alloc(300 * 640 * 2);
    u16* w2hi = (u16*)alloc(300 * 640 * 2);
    u16* w2lo = (u16*)alloc(300 * 640 * 2);
    u16* w3hi = (u16*)alloc(300 * 320 * 2);
    u16* w3lo = (u16*)alloc(300 * 320 * 2);
    u16* featb_hi = (u16*)alloc(planeB);
    u16* featb_lo = (u16*)alloc(planeB);
    u16* aggb_hi = (u16*)alloc(planeB);
    u16* aggb_lo = (u16*)alloc(planeB);
    u16* x1hi = (u16*)alloc(planeB);
    u16* x1lo = (u16*)alloc(planeB);
    u16* x2hi = featb_hi;   // featb dead after GEMM1
    u16* x2lo = featb_lo;
    (void)ws_size; (void)n_in; (void)out_size;

    hipMemsetAsync(cursor, 0, (size_t)M * 4, stream);
    hipMemsetAsync(sumsq, 0, 4, stream);
    hipMemsetAsync(flag, 0, 4, stream);

    const int tb = 256;
    detect_kernel<<<256, tb, 0, stream>>>((const unsigned int*)src, (const unsigned int*)dst,
                                          nE, flag);
    hist_kernel<<<(nE + tb - 1) / tb, tb, 0, stream>>>(dst, flag, cursor, nE);
    scan_kernel<<<1, 1024, 0, stream>>>(cursor, offsets, M);
    fill_kernel<<<(nE + tb - 1) / tb, tb, 0, stream>>>(src, dst, flag, cursor, eidx, nE);

    conv_feat<<<(M * 76 + tb - 1) / tb, tb, 0, stream>>>(feat, featb_hi, featb_lo, M);
    conv_w<<<(300 * 640 + tb - 1) / tb, tb, 0, stream>>>(W1, w1hi, w1lo, 2);
    conv_w<<<(300 * 640 + tb - 1) / tb, tb, 0, stream>>>(W2, w2hi, w2lo, 2);
    conv_w<<<(300 * 320 + tb - 1) / tb, tb, 0, stream>>>(W3, w3hi, w3lo, 1);

    const int Mt = (M + BM - 1) / BM;        // 391
    const int NBt = (DD + BN - 1) / BN;      // 5
    const int nwg = Mt * NBt;                // 1955

    // layer 1
    agg_bf16<<<M, 64, 0, stream>>>(featb_hi, featb_lo, eidx, offsets, aggb_hi, aggb_lo);
    mfma_gemm<2, 0><<<nwg, 256, 0, stream>>>(featb_hi, featb_lo, aggb_hi, aggb_lo,
                                             w1hi, w1lo, b1, M, NBt,
                                             x1hi, x1lo, nullptr, nullptr);
    // layer 2
    agg_bf16<<<M, 64, 0, stream>>>(x1hi, x1lo, eidx, offsets, aggb_hi, aggb_lo);
    mfma_gemm<2, 1><<<nwg, 256, 0, stream>>>(x1hi, x1lo, aggb_hi, aggb_lo,
                                             w2hi, w2lo, b2, M, NBt,
                                             x2hi, x2lo, nullptr, nullptr);
    // output layer
    mfma_gemm<1, 2><<<nwg, 256, 0, stream>>>(x2hi, x2lo, nullptr, nullptr,
                                             w3hi, w3lo, b3, M, NBt,
                                             nullptr, nullptr, out, sumsq);
    // global frobenius normalize
    int n4 = (M * DD) / 4;
    norm_kernel<<<(n4 + tb - 1) / tb, tb, 0, stream>>>(out, sumsq, n4);
}

// Round 5
// 1001.140 us; speedup vs baseline: 1.3495x; 1.0744x over previous
//
#include <hip/hip_runtime.h>
#include <cstdint>
#include <cstddef>

typedef unsigned short u16;
typedef __attribute__((ext_vector_type(8))) short short8;
typedef __attribute__((ext_vector_type(4))) float f32x4;

#define DD 300
#define KPAD 304           // activation row length in bf16 (608 B rows)
#define BM 128
#define BN 64

__device__ __forceinline__ u16 f2bf(float f) {
    unsigned u = __float_as_uint(f);
    unsigned r = (u + 0x7fffu + ((u >> 16) & 1u)) >> 16;   // RNE
    return (u16)r;
}
__device__ __forceinline__ float bf2f(u16 h) {
    return __uint_as_float((unsigned)h << 16);
}

#define GLOAD16(SRC, DST) \
    __builtin_amdgcn_global_load_lds((const __attribute__((address_space(1))) void*)(SRC), \
                                     (__attribute__((address_space(3))) void*)(DST), 16, 0, 0)

// ---------------- index dtype detection (int32 vs int64 indices) ----------------
__global__ void detect_kernel(const unsigned int* __restrict__ a,
                              const unsigned int* __restrict__ b,
                              int nWords, unsigned int* __restrict__ flag) {
    unsigned int v = 0;
    int stride = gridDim.x * blockDim.x;
    for (int i = blockIdx.x * blockDim.x + threadIdx.x; i < nWords / 2; i += stride)
        v |= a[2 * i + 1] | b[2 * i + 1];
    if (v) atomicOr(flag, 1u);
}

__device__ __forceinline__ int load_idx(const void* p, int e, bool is64) {
    return is64 ? (int)((const long long*)p)[e] : ((const int*)p)[e];
}

// ---------------- CSR build ----------------
__global__ void hist_kernel(const void* __restrict__ dst, const unsigned int* __restrict__ flag,
                            int* __restrict__ counts, int nE) {
    int e = blockIdx.x * blockDim.x + threadIdx.x;
    if (e < nE) {
        bool is64 = (*flag == 0u);
        atomicAdd(&counts[load_idx(dst, e, is64)], 1);
    }
}

__global__ void scan_kernel(int* __restrict__ cnt_cursor, int* __restrict__ offsets, int n) {
    __shared__ int sums[1024];
    int t = threadIdx.x;
    int CH = (n + 1023) >> 10;
    int base = t * CH;
    int s = 0;
    for (int i = 0; i < CH; ++i) {
        int idx = base + i;
        if (idx < n) s += cnt_cursor[idx];
    }
    sums[t] = s;
    __syncthreads();
    for (int off = 1; off < 1024; off <<= 1) {
        int v = (t >= off) ? sums[t - off] : 0;
        __syncthreads();
        sums[t] += v;
        __syncthreads();
    }
    int run = (t == 0) ? 0 : sums[t - 1];
    for (int i = 0; i < CH; ++i) {
        int idx = base + i;
        if (idx < n) {
            int c = cnt_cursor[idx];
            offsets[idx] = run;
            cnt_cursor[idx] = run;
            run += c;
        }
    }
    if (t == 1023) offsets[n] = sums[1023];
}

__global__ void fill_kernel(const void* __restrict__ src, const void* __restrict__ dst,
                            const unsigned int* __restrict__ flag,
                            int* __restrict__ cursor, int* __restrict__ eidx, int nE) {
    int e = blockIdx.x * blockDim.x + threadIdx.x;
    if (e < nE) {
        bool is64 = (*flag == 0u);
        int d = load_idx(dst, e, is64);
        int s = load_idx(src, e, is64);
        int pos = atomicAdd(&cursor[d], 1);
        eidx[pos] = s;
    }
}

// ---------------- f32 -> bf16 hi/lo conversion ----------------
__global__ void conv_feat(const float* __restrict__ src, u16* __restrict__ dhi,
                          u16* __restrict__ dlo, int M) {
    int tid = blockIdx.x * blockDim.x + threadIdx.x;
    int total = M * 76;
    if (tid >= total) return;
    int row = tid / 76, cq = tid - row * 76;
    int k = cq * 4;
    float vx = 0.f, vy = 0.f, vz = 0.f, vw = 0.f;
    if (k < DD) {
        float4 v = *(const float4*)(src + (size_t)row * DD + k);
        vx = v.x; vy = v.y; vz = v.z; vw = v.w;
    }
    ushort4 h, l;
    h.x = f2bf(vx); l.x = f2bf(vx - bf2f(h.x));
    h.y = f2bf(vy); l.y = f2bf(vy - bf2f(h.y));
    h.z = f2bf(vz); l.z = f2bf(vz - bf2f(h.z));
    h.w = f2bf(vw); l.w = f2bf(vw - bf2f(h.w));
    *(ushort4*)&dhi[(size_t)row * KPAD + k] = h;
    *(ushort4*)&dlo[(size_t)row * KPAD + k] = l;
}

// W: [300][nseg*300] f32 row-major -> whi/wlo [300][nseg*320] bf16 (zero-padded k 300..319/seg)
__global__ void conv_w(const float* __restrict__ W, u16* __restrict__ whi,
                       u16* __restrict__ wlo, int nseg) {
    int KP = nseg * 320;
    int tid = blockIdx.x * blockDim.x + threadIdx.x;
    if (tid >= 300 * KP) return;
    int n = tid / KP, kk = tid - n * KP;
    int seg = kk / 320, ko = kk - seg * 320;
    float v = (ko < DD) ? W[(size_t)n * (nseg * DD) + seg * DD + ko] : 0.f;
    u16 h = f2bf(v);
    whi[tid] = h;
    wlo[tid] = f2bf(v - bf2f(h));
}

// ---------------- aggregation over bf16 hi/lo planes ----------------
__global__ __launch_bounds__(64)
void agg_bf16(const u16* __restrict__ xhi, const u16* __restrict__ xlo,
              const int* __restrict__ eidx, const int* __restrict__ offsets,
              u16* __restrict__ ohi, u16* __restrict__ olo) {
    int v = blockIdx.x, lane = threadIdx.x;
    int beg = offsets[v], end = offsets[v + 1];
    float am0 = 0.f, am1 = 0.f, am2 = 0.f, am3 = 0.f;
    float at0 = 0.f, at1 = 0.f, at2 = 0.f, at3 = 0.f;
    bool tail = lane < 11;                     // chunks 64..74 cover k 256..299
    for (int i = beg; i < end; ++i) {
        size_t base = (size_t)eidx[i] * KPAD;
        ushort4 h = *(const ushort4*)&xhi[base + lane * 4];
        ushort4 l = *(const ushort4*)&xlo[base + lane * 4];
        am0 += bf2f(h.x) + bf2f(l.x);
        am1 += bf2f(h.y) + bf2f(l.y);
        am2 += bf2f(h.z) + bf2f(l.z);
        am3 += bf2f(h.w) + bf2f(l.w);
        if (tail) {
            ushort4 h2 = *(const ushort4*)&xhi[base + 256 + lane * 4];
            ushort4 l2 = *(const ushort4*)&xlo[base + 256 + lane * 4];
            at0 += bf2f(h2.x) + bf2f(l2.x);
            at1 += bf2f(h2.y) + bf2f(l2.y);
            at2 += bf2f(h2.z) + bf2f(l2.z);
            at3 += bf2f(h2.w) + bf2f(l2.w);
        }
    }
    size_t ob = (size_t)v * KPAD + lane * 4;
    ushort4 oh, ol;
    oh.x = f2bf(am0); ol.x = f2bf(am0 - bf2f(oh.x));
    oh.y = f2bf(am1); ol.y = f2bf(am1 - bf2f(oh.y));
    oh.z = f2bf(am2); ol.z = f2bf(am2 - bf2f(oh.z));
    oh.w = f2bf(am3); ol.w = f2bf(am3 - bf2f(oh.w));
    *(ushort4*)&ohi[ob] = oh;
    *(ushort4*)&olo[ob] = ol;
    if (tail) {
        size_t ob2 = (size_t)v * KPAD + 256 + lane * 4;
        ushort4 oh2, ol2;
        oh2.x = f2bf(at0); ol2.x = f2bf(at0 - bf2f(oh2.x));
        oh2.y = f2bf(at1); ol2.y = f2bf(at1 - bf2f(oh2.y));
        oh2.z = f2bf(at2); ol2.z = f2bf(at2 - bf2f(oh2.z));
        oh2.w = f2bf(at3); ol2.w = f2bf(at3 - bf2f(oh2.w));
        *(ushort4*)&ohi[ob2] = oh2;
        *(ushort4*)&olo[ob2] = ol2;
    }
}

// ---------------- MFMA GEMM: C = act( sum_seg A_seg @ Wseg.T + b ) ----------------
// Split-bf16: per k-tile stage 4 planes (Ahi,Alo,Bhi,Blo) ONCE, then 3 register
// passes: AhiBhi, AhiBlo, AloBhi (same accumulation order as before -> numerics
// identical). 20 barriers instead of 60; A-hi staged once instead of twice.
// ACT 0: leaky_relu -> bf16 hi/lo planes; 1: identity -> planes; 2: tanh -> f32 + sumsq.
template<int NSEG, int ACT>
__global__ __launch_bounds__(256)
void mfma_gemm(const u16* __restrict__ A0hi, const u16* __restrict__ A0lo,
               const u16* __restrict__ A1hi, const u16* __restrict__ A1lo,
               const u16* __restrict__ Bhi, const u16* __restrict__ Blo,
               const float* __restrict__ bias, int M, int NB,
               u16* __restrict__ Ohi, u16* __restrict__ Olo,
               float* __restrict__ outf, float* __restrict__ sumsq) {
    constexpr int NKT = NSEG * 10;         // k-tiles of 32 bf16 (64 B)
    constexpr int BROW = NSEG * 640;       // B row bytes
    // per buffer: Ahi 8192 | Alo 8192 | Bhi 4096 | Blo 4096 = 24576 B
    constexpr int ALO = 8192, BHI = 16384, BLO = 20480, BUF = 24576;
    __shared__ __align__(16) char lds[2 * BUF];
    __shared__ float red[256];

    const int t = threadIdx.x;
    const int w = t >> 6, lane = t & 63;
    const int wm = w >> 1, wn = w & 1;
    const int lr = lane & 15, loct = lane >> 4;

    // XCD-chunked bijective swizzle (m204 form)
    int nwg = gridDim.x;
    int q = nwg >> 3, r = nwg & 7;
    int xc = blockIdx.x & 7, o8 = blockIdx.x >> 3;
    int wg = (xc < r ? xc * (q + 1) : r * (q + 1) + (xc - r) * q) + o8;
    int nt = wg % NB, mt = wg / NB;
    const int m0 = mt * BM, col0 = nt * BN;

    f32x4 acc[4][2];
#pragma unroll
    for (int mi = 0; mi < 4; ++mi)
#pragma unroll
        for (int ni = 0; ni < 2; ++ni) {
            f32x4 z = {0.f, 0.f, 0.f, 0.f};
            acc[mi][ni] = z;
        }

    auto stage = [&](int buf, int ktg) {
        int seg = (NSEG == 2) ? (ktg / 10) : 0;
        int kt = (NSEG == 2) ? (ktg - seg * 10) : ktg;
        const char* Ahp = (const char*)((NSEG == 2 && seg) ? A1hi : A0hi);
        const char* Alp = (const char*)((NSEG == 2 && seg) ? A1lo : A0lo);
        int Ak = kt * 64;
        int Bk = seg * 640 + kt * 64;
        char* base = lds + buf * BUF;
#pragma unroll
        for (int a2 = 0; a2 < 2; ++a2) {
            int rowi = m0 + a2 * 64 + lane;
            rowi = rowi < M ? rowi : (M - 1);
            size_t ro = (size_t)rowi * 608 + Ak + w * 16;
            GLOAD16(Ahp + ro, base + (2 * w + a2) * 1024);
            GLOAD16(Alp + ro, base + ALO + (2 * w + a2) * 1024);
        }
        int coli = col0 + lane;
        coli = coli < DD ? coli : (DD - 1);
        size_t co = (size_t)coli * BROW + Bk + w * 16;
        GLOAD16((const char*)Bhi + co, base + BHI + w * 1024);
        GLOAD16((const char*)Blo + co, base + BLO + w * 1024);
    };

    stage(0, 0);
    for (int ktg = 0; ktg < NKT; ++ktg) {
        __syncthreads();                    // vmcnt(0) drain -> buf (ktg&1) ready
        if (ktg + 1 < NKT) stage((ktg + 1) & 1, ktg + 1);
        const char* base = lds + (ktg & 1) * BUF;
        // fragment loads (12 x ds_read_b128)
        short8 ah[4], al[4], bh[2], bl[2];
#pragma unroll
        for (int mi = 0; mi < 4; ++mi) {
            int aoff = (loct * 128 + wm * 64 + mi * 16 + lr) * 16;
            ah[mi] = *(const short8*)(base + aoff);
            al[mi] = *(const short8*)(base + ALO + aoff);
        }
#pragma unroll
        for (int ni = 0; ni < 2; ++ni) {
            int boff = (loct * 64 + wn * 32 + ni * 16 + lr) * 16;
            bh[ni] = *(const short8*)(base + BHI + boff);
            bl[ni] = *(const short8*)(base + BLO + boff);
        }
        // pass 0: Ahi*Bhi (same order as previous version)
#pragma unroll
        for (int mi = 0; mi < 4; ++mi) {
            acc[mi][0] = __builtin_amdgcn_mfma_f32_16x16x32_bf16(ah[mi], bh[0], acc[mi][0], 0, 0, 0);
            acc[mi][1] = __builtin_amdgcn_mfma_f32_16x16x32_bf16(ah[mi], bh[1], acc[mi][1], 0, 0, 0);
        }
        // pass 1: Ahi*Blo
#pragma unroll
        for (int mi = 0; mi < 4; ++mi) {
            acc[mi][0] = __builtin_amdgcn_mfma_f32_16x16x32_bf16(ah[mi], bl[0], acc[mi][0], 0, 0, 0);
            acc[mi][1] = __builtin_amdgcn_mfma_f32_16x16x32_bf16(ah[mi], bl[1], acc[mi][1], 0, 0, 0);
        }
        // pass 2: Alo*Bhi
#pragma unroll
        for (int mi = 0; mi < 4; ++mi) {
            acc[mi][0] = __builtin_amdgcn_mfma_f32_16x16x32_bf16(al[mi], bh[0], acc[mi][0], 0, 0, 0);
            acc[mi][1] = __builtin_amdgcn_mfma_f32_16x16x32_bf16(al[mi], bh[1], acc[mi][1], 0, 0, 0);
        }
    }

    // epilogue: C row = m0 + wm*64 + mi*16 + loct*4 + rg ; col = col0 + wn*32 + ni*16 + lr
    float ss = 0.f;
#pragma unroll
    for (int mi = 0; mi < 4; ++mi)
#pragma unroll
        for (int ni = 0; ni < 2; ++ni) {
            int col = col0 + wn * 32 + ni * 16 + lr;
            bool cok = col < DD;
            float bv = cok ? bias[col] : 0.f;
#pragma unroll
            for (int rg = 0; rg < 4; ++rg) {
                int row = m0 + wm * 64 + mi * 16 + loct * 4 + rg;
                if (cok && row < M) {
                    float v = acc[mi][ni][rg] + bv;
                    if (ACT == 0) v = v > 0.f ? v : 0.01f * v;
                    if (ACT <= 1) {
                        u16 h = f2bf(v);
                        u16 l = f2bf(v - bf2f(h));
                        Ohi[(size_t)row * KPAD + col] = h;
                        Olo[(size_t)row * KPAD + col] = l;
                    } else {
                        float tv = tanhf(v);
                        outf[(size_t)row * DD + col] = tv;
                        ss += tv * tv;
                    }
                }
            }
        }
    if (ACT == 2) {
        red[t] = ss;
        __syncthreads();
        for (int s2 = 128; s2 > 0; s2 >>= 1) {
            if (t < s2) red[t] += red[t + s2];
            __syncthreads();
        }
        if (t == 0) atomicAdd(sumsq, red[0]);
    }
}

__global__ void norm_kernel(float* __restrict__ out, const float* __restrict__ sumsq, int n4) {
    int i = blockIdx.x * blockDim.x + threadIdx.x;
    if (i < n4) {
        float inv = rsqrtf(*sumsq);
        float4* o = (float4*)out;
        float4 v = o[i];
        v.x *= inv; v.y *= inv; v.z *= inv; v.w *= inv;
        o[i] = v;
    }
}

// ---------------- launch ----------------
extern "C" void kernel_launch(void* const* d_in, const int* in_sizes, int n_in,
                              void* d_out, int out_size, void* d_ws, size_t ws_size,
                              hipStream_t stream) {
    const float* feat = (const float*)d_in[0];
    const void* src = d_in[1];
    const void* dst = d_in[2];
    const float* W1 = (const float*)d_in[3];
    const float* b1 = (const float*)d_in[4];
    const float* W2 = (const float*)d_in[5];
    const float* b2 = (const float*)d_in[6];
    const float* W3 = (const float*)d_in[7];
    const float* b3 = (const float*)d_in[8];
    float* out = (float*)d_out;

    const int M = in_sizes[0] / DD;    // 50000
    const int nE = in_sizes[1];        // 800000

    char* ws = (char*)d_ws;
    size_t off = 0;
    auto alloc = [&](size_t bytes) -> void* {
        off = (off + 255) & ~(size_t)255;
        void* p = ws + off;
        off += bytes;
        return p;
    };
    const size_t planeB = (size_t)M * KPAD * 2 + 256;   // +slack for kt=9 overread
    int* eidx = (int*)alloc((size_t)nE * 4);
    int* offsets = (int*)alloc((size_t)(M + 1) * 4);
    int* cursor = (int*)alloc((size_t)M * 4);
    float* sumsq = (float*)alloc(4);
    unsigned int* flag = (unsigned int*)alloc(4);
    u16* w1hi = (u16*)alloc(300 * 640 * 2);
    u16* w1lo = (u16*)alloc(300 * 640 * 2);
    u16* w2hi = (u16*)alloc(300 * 640 * 2);
    u16* w2lo = (u16*)alloc(300 * 640 * 2);
    u16* w3hi = (u16*)alloc(300 * 320 * 2);
    u16* w3lo = (u16*)alloc(300 * 320 * 2);
    u16* featb_hi = (u16*)alloc(planeB);
    u16* featb_lo = (u16*)alloc(planeB);
    u16* aggb_hi = (u16*)alloc(planeB);
    u16* aggb_lo = (u16*)alloc(planeB);
    u16* x1hi = (u16*)alloc(planeB);
    u16* x1lo = (u16*)alloc(planeB);
    u16* x2hi = featb_hi;   // featb dead after GEMM1
    u16* x2lo = featb_lo;
    (void)ws_size; (void)n_in; (void)out_size;

    hipMemsetAsync(cursor, 0, (size_t)M * 4, stream);
    hipMemsetAsync(sumsq, 0, 4, stream);
    hipMemsetAsync(flag, 0, 4, stream);

    const int tb = 256;
    detect_kernel<<<256, tb, 0, stream>>>((const unsigned int*)src, (const unsigned int*)dst,
                                          nE, flag);
    hist_kernel<<<(nE + tb - 1) / tb, tb, 0, stream>>>(dst, flag, cursor, nE);
    scan_kernel<<<1, 1024, 0, stream>>>(cursor, offsets, M);
    fill_kernel<<<(nE + tb - 1) / tb, tb, 0, stream>>>(src, dst, flag, cursor, eidx, nE);

    conv_feat<<<(M * 76 + tb - 1) / tb, tb, 0, stream>>>(feat, featb_hi, featb_lo, M);
    conv_w<<<(300 * 640 + tb - 1) / tb, tb, 0, stream>>>(W1, w1hi, w1lo, 2);
    conv_w<<<(300 * 640 + tb - 1) / tb, tb, 0, stream>>>(W2, w2hi, w2lo, 2);
    conv_w<<<(300 * 320 + tb - 1) / tb, tb, 0, stream>>>(W3, w3hi, w3lo, 1);

    const int Mt = (M + BM - 1) / BM;        // 391
    const int NBt = (DD + BN - 1) / BN;      // 5
    const int nwg = Mt * NBt;                // 1955

    // layer 1
    agg_bf16<<<M, 64, 0, stream>>>(featb_hi, featb_lo, eidx, offsets, aggb_hi, aggb_lo);
    mfma_gemm<2, 0><<<nwg, 256, 0, stream>>>(featb_hi, featb_lo, aggb_hi, aggb_lo,
                                             w1hi, w1lo, b1, M, NBt,
                                             x1hi, x1lo, nullptr, nullptr);
    // layer 2
    agg_bf16<<<M, 64, 0, stream>>>(x1hi, x1lo, eidx, offsets, aggb_hi, aggb_lo);
    mfma_gemm<2, 1><<<nwg, 256, 0, stream>>>(x1hi, x1lo, aggb_hi, aggb_lo,
                                             w2hi, w2lo, b2, M, NBt,
                                             x2hi, x2lo, nullptr, nullptr);
    // output layer
    mfma_gemm<1, 2><<<nwg, 256, 0, stream>>>(x2hi, x2lo, nullptr, nullptr,
                                             w3hi, w3lo, b3, M, NBt,
                                             nullptr, nullptr, out, sumsq);
    // global frobenius normalize
    int n4 = (M * DD) / 4;
    norm_kernel<<<(n4 + tb - 1) / tb, tb, 0, stream>>>(out, sumsq, n4);
}